// Round 1
// baseline (153.309 us; speedup 1.0000x reference)
//
#include <hip/hip_runtime.h>
#include <math.h>

#define N_POINTS 16384
#define N_CLOUDS 8
#define KMAX 64

constexpr double R2D = 1.0 / 256.0;   // (1/16)^2, exact in binary

// ---------------------------------------------------------------------------
// K1: cloud range binary search + pos copy + batch->float copy
// ---------------------------------------------------------------------------
__global__ __launch_bounds__(256) void k_prep(const float* __restrict__ pos,
                                              const int* __restrict__ batch,
                                              float* __restrict__ out,
                                              int* __restrict__ cloud_start)
{
    int tid = blockIdx.x * blockDim.x + threadIdx.x;
    if (blockIdx.x == 0 && threadIdx.x <= N_CLOUDS) {
        // cloud_start[c] = lower_bound(batch, c)
        int c = threadIdx.x;
        int lo = 0, hi = N_POINTS;
        while (lo < hi) {
            int mid = (lo + hi) >> 1;
            if (batch[mid] < c) lo = mid + 1; else hi = mid;
        }
        cloud_start[c] = lo;
    }
    int stride = gridDim.x * blockDim.x;
    // output 0: pos copy [N,3]
    for (int i = tid; i < N_POINTS * 3; i += stride) out[i] = pos[i];
    // output 2: batch as float, after pos (3N) and out (32N)
    for (int i = tid; i < N_POINTS; i += stride)
        out[N_POINTS * 3 + N_POINTS * 32 + i] = (float)batch[i];
}

// ---------------------------------------------------------------------------
// K2: radius search (fp64 distance) fused with layer a (PointNetConv 6->8->8)
// One wave (64 lanes) per point. ~2 hits expected per point.
// ---------------------------------------------------------------------------
__global__ __launch_bounds__(256) void k_search_a(
    const float* __restrict__ pos, const int* __restrict__ batch,
    const int* __restrict__ cloud_start,
    const float* __restrict__ W1, const float* __restrict__ b1,
    const float* __restrict__ W2, const float* __restrict__ b2,
    float* __restrict__ out_a, int* __restrict__ nbr_idx, int* __restrict__ nbr_cnt)
{
    __shared__ float sW1[48], sB1[8], sW2[64], sB2[8];
    __shared__ int   s_cnt[4];
    __shared__ int   s_list[4][KMAX];

    int t = threadIdx.x;
    if      (t < 48)  sW1[t]       = W1[t];
    else if (t < 56)  sB1[t - 48]  = b1[t - 48];
    else if (t < 120) sW2[t - 56]  = W2[t - 56];
    else if (t < 128) sB2[t - 120] = b2[t - 120];

    int wave = t >> 6, lane = t & 63;
    if (lane == 0) s_cnt[wave] = 0;
    __syncthreads();

    int i = blockIdx.x * 4 + wave;                    // grid = N/4 exactly
    float xi = pos[3 * i], yi = pos[3 * i + 1], zi = pos[3 * i + 2];
    int c = batch[i];
    int s = cloud_start[c], e = cloud_start[c + 1];
    double xd = (double)xi, yd = (double)yi, zd = (double)zi;

    float mx[8];
#pragma unroll
    for (int m = 0; m < 8; m++) mx[m] = 0.f;          // relu msgs >= 0, self always valid

    for (int j = s + lane; j < e; j += 64) {
        float xj = pos[3 * j], yj = pos[3 * j + 1], zj = pos[3 * j + 2];
        double dx = xd - (double)xj, dy = yd - (double)yj, dz = zd - (double)zj;
        double d2 = dx * dx + dy * dy + dz * dz;
        if (d2 <= R2D) {
            int slot = atomicAdd(&s_cnt[wave], 1);
            if (slot < KMAX) s_list[wave][slot] = j;
            float in6[6] = { xj, yj, zj, xj - xi, yj - yi, zj - zi };
#pragma unroll
            for (int m = 0; m < 8; m++) {
                float h = sB1[m];
#pragma unroll
                for (int k = 0; k < 6; k++) h = fmaf(in6[k], sW1[k * 8 + m], h);
                mx[m] = fmaxf(mx[m], fmaxf(h, 0.f));
            }
        }
    }

    // wave-wide max reduction (butterfly over 64 lanes)
#pragma unroll
    for (int off = 32; off; off >>= 1)
#pragma unroll
        for (int m = 0; m < 8; m++)
            mx[m] = fmaxf(mx[m], __shfl_xor(mx[m], off));

    int cnt = min(s_cnt[wave], KMAX);
    if (lane == 0) nbr_cnt[i] = cnt;
    for (int tt = lane; tt < cnt; tt += 64) nbr_idx[i * KMAX + tt] = s_list[wave][tt];

    if (lane < 8) {
        int m = lane;
        float o = sB2[m];
#pragma unroll
        for (int k = 0; k < 8; k++) o = fmaf(mx[k], sW2[k * 8 + m], o);
        out_a[i * 8 + m] = o > 0.f ? o : expm1f(o);   // celu, alpha=1
    }
}

// ---------------------------------------------------------------------------
// K3/K4: PointNetConv over recorded neighbor lists.
// thread = (point p, channel m); CMID == COUT; PTS * CMID == 256.
// ---------------------------------------------------------------------------
template<int CIN, int CMID, int COUT, int PTS>
__global__ __launch_bounds__(256) void k_conv(
    const float* __restrict__ pos, const float* __restrict__ xin,
    const int* __restrict__ nbr_idx, const int* __restrict__ nbr_cnt,
    const float* __restrict__ W1, const float* __restrict__ b1,
    const float* __restrict__ W2, const float* __restrict__ b2,
    float* __restrict__ xout)
{
    __shared__ float s_agg[PTS][CMID];
    int p = threadIdx.x / CMID;
    int m = threadIdx.x % CMID;
    int i = blockIdx.x * PTS + p;

    float xi = pos[3 * i], yi = pos[3 * i + 1], zi = pos[3 * i + 2];
    int cnt = nbr_cnt[i];

    float w1c[CIN + 3];
#pragma unroll
    for (int k = 0; k < CIN + 3; k++) w1c[k] = W1[k * CMID + m];
    float bb = b1[m];

    float mx = 0.f;                                   // self always valid, relu >= 0
    for (int t = 0; t < cnt; t++) {
        int j = nbr_idx[i * KMAX + t];
        float h = bb;
#pragma unroll
        for (int k = 0; k < CIN; k++) h = fmaf(xin[j * CIN + k], w1c[k], h);
        h = fmaf(pos[3 * j]     - xi, w1c[CIN + 0], h);
        h = fmaf(pos[3 * j + 1] - yi, w1c[CIN + 1], h);
        h = fmaf(pos[3 * j + 2] - zi, w1c[CIN + 2], h);
        mx = fmaxf(mx, fmaxf(h, 0.f));
    }
    s_agg[p][m] = mx;
    __syncthreads();

    float o = b2[m];
#pragma unroll
    for (int k = 0; k < CMID; k++) o = fmaf(s_agg[p][k], W2[k * COUT + m], o);
    xout[i * COUT + m] = o > 0.f ? o : expm1f(o);     // celu, alpha=1
}

// ---------------------------------------------------------------------------
extern "C" void kernel_launch(void* const* d_in, const int* in_sizes, int n_in,
                              void* d_out, int out_size, void* d_ws, size_t ws_size,
                              hipStream_t stream)
{
    const float* pos   = (const float*)d_in[0];
    // d_in[1] = rgb: unused by reference
    const int*   batch = (const int*)d_in[2];
    const float* W1a = (const float*)d_in[3];
    const float* b1a = (const float*)d_in[4];
    const float* W2a = (const float*)d_in[5];
    const float* b2a = (const float*)d_in[6];
    const float* W1b = (const float*)d_in[7];
    const float* b1b = (const float*)d_in[8];
    const float* W2b = (const float*)d_in[9];
    const float* b2b = (const float*)d_in[10];
    const float* W1c = (const float*)d_in[11];
    const float* b1c = (const float*)d_in[12];
    const float* W2c = (const float*)d_in[13];
    const float* b2c = (const float*)d_in[14];

    float* out = (float*)d_out;

    char* ws = (char*)d_ws;
    int*   cloud_start = (int*)ws;                                    // 16 ints
    int*   nbr_cnt = (int*)(ws + 64);                                 // N ints
    int*   nbr_idx = (int*)(ws + 64 + 4 * N_POINTS);                  // N*64 ints
    float* out_a   = (float*)(ws + 64 + 4 * N_POINTS + 4 * N_POINTS * KMAX);
    float* out_b   = (float*)((char*)out_a + 4 * N_POINTS * 8);

    hipLaunchKernelGGL(k_prep, dim3(64), dim3(256), 0, stream,
                       pos, batch, out, cloud_start);
    hipLaunchKernelGGL(k_search_a, dim3(N_POINTS / 4), dim3(256), 0, stream,
                       pos, batch, cloud_start, W1a, b1a, W2a, b2a,
                       out_a, nbr_idx, nbr_cnt);
    hipLaunchKernelGGL((k_conv<8, 16, 16, 16>), dim3(N_POINTS / 16), dim3(256), 0, stream,
                       pos, out_a, nbr_idx, nbr_cnt, W1b, b1b, W2b, b2b, out_b);
    hipLaunchKernelGGL((k_conv<16, 32, 32, 8>), dim3(N_POINTS / 8), dim3(256), 0, stream,
                       pos, out_b, nbr_idx, nbr_cnt, W1c, b1c, W2c, b2c,
                       out + 3 * N_POINTS);
}